// Round 13
// baseline (130.962 us; speedup 1.0000x reference)
//
#include <hip/hip_runtime.h>
#include <stdint.h>

#define NE 8
#define ND 512
#define NH1 512
#define NH2 256
#define NY 256
#define NB 8192
#define BM3 32                   /* fused-tile rows */
#define MAXT3 (NB/BM3 + NE - 1)  /* 263 */
/* 64x64 transpose tiles */
#define W1T64 (NE * (ND/64) * (NH1/64))   /* 512 */
#define W2T64 (NE * (NH1/64) * (NH2/64))  /* 256 */
#define W3T64 (NE * (NH2/64) * (NY/64))   /* 128 */
#define WTT64 (W1T64 + W2T64 + W3T64)     /* 896 */

typedef float f32x4 __attribute__((ext_vector_type(4)));
typedef __bf16 bf16x8 __attribute__((ext_vector_type(8)));
typedef unsigned short u16x8 __attribute__((ext_vector_type(8)));

__device__ __forceinline__ unsigned short f2bf(float f) {
  unsigned int u = __float_as_uint(f);
  u += 0x7fffu + ((u >> 16) & 1u);   // round-to-nearest-even
  return (unsigned short)(u >> 16);
}

__device__ __forceinline__ int clampe(int g) {
  return g < 0 ? 0 : (g > NE - 1 ? NE - 1 : g);
}

// Fragment-order W layout: element (k = kt*32 + (lane>>4)*8 + j, n = f*16 + (lane&15))
// lives at Wf[(((kt * (N/16)) + f) * 64 + lane) * 8 + j].

// meta ints: [0..7] counts, [8..15] offs, [24] ntiles, [1024..1310] tile table

__global__ __launch_bounds__(256)
void prep_k(const int* __restrict__ gate,
            const float* __restrict__ W1, const float* __restrict__ W2,
            const float* __restrict__ W3,
            unsigned short* __restrict__ w1f, unsigned short* __restrict__ w2f,
            unsigned short* __restrict__ w3f,
            int* __restrict__ meta, int* __restrict__ perm)
{
  __shared__ char sm[17024] __attribute__((aligned(16)));
  int b = blockIdx.x, t = threadIdx.x;

  if (b < WTT64) {
    float* ldsf = (float*)sm;   // [64][65]
    const float* src; unsigned short* dst; int K, N, idx;
    if (b < W1T64)          { src = W1; dst = w1f; K = ND;  N = NH1; idx = b; }
    else if (b < W1T64 + W2T64) { src = W2; dst = w2f; K = NH1; N = NH2; idx = b - W1T64; }
    else                    { src = W3; dst = w3f; K = NH2; N = NY;  idx = b - W1T64 - W2T64; }
    int ntn = N >> 6, ntk = K >> 6;
    int n0 = (idx % ntn) * 64;
    int k0 = ((idx / ntn) % ntk) * 64;
    int g  = idx / (ntn * ntk);
    {
      int r  = t >> 2;
      int c4 = t & 3;
      const float* s = src + (size_t)g * K * N + (size_t)(k0 + r) * N + n0;
      #pragma unroll
      for (int i = 0; i < 4; i++) {
        float4 v = *(const float4*)(s + (i * 4 + c4) * 4);
        *(float4*)(ldsf + r * 65 + (i * 4 + c4) * 4) = v;
      }
    }
    __syncthreads();
    unsigned short* d = dst + (size_t)g * K * N;
    #pragma unroll
    for (int ii = 0; ii < 2; ii++) {
      int idx2 = ii * 256 + t;
      int lane = idx2 & 63;
      int f    = (idx2 >> 6) & 3;
      int kt   = idx2 >> 8;
      int kl   = kt * 32 + (lane >> 4) * 8;
      int nl   = f * 16 + (lane & 15);
      union { u16x8 v; unsigned short u[8]; } pk;
      #pragma unroll
      for (int j = 0; j < 8; j++)
        pk.u[j] = f2bf(ldsf[(kl + j) * 65 + nl]);
      int ktg = (k0 >> 5) + kt;
      int fg  = (n0 >> 4) + f;
      *(u16x8*)(d + (((size_t)ktg * (N >> 4) + fg) * 64 + lane) * 8) = pk.v;
    }
    return;
  }

  // ---- sort block ----
  unsigned int* lcnt_lo = (unsigned int*)sm;
  unsigned int* lcnt_hi = lcnt_lo + 256;
  int* pre   = (int*)(sm + 2048);
  int* cnt8  = (int*)(sm + 2048 + 8192);
  int* offs8 = cnt8 + 8;

  unsigned int gp[8];
  unsigned int clo = 0, chi = 0;
  #pragma unroll
  for (int i = 0; i < 32; i++) {
    int g = clampe(gate[t * 32 + i]);
    if ((i & 3) == 0) gp[i >> 2] = 0;
    gp[i >> 2] |= (unsigned int)g << (8 * (i & 3));
    if (g < 4) clo += 1u << (8 * g);
    else       chi += 1u << (8 * (g - 4));
  }
  lcnt_lo[t] = clo;
  lcnt_hi[t] = chi;
  __syncthreads();

  int wave = t >> 6, lane = t & 63;
  #pragma unroll
  for (int pass = 0; pass < 2; pass++) {
    int e = wave + pass * 4;
    int carry = 0;
    #pragma unroll
    for (int ch = 0; ch < 4; ch++) {
      int idx = ch * 64 + lane;
      unsigned int word = (e < 4) ? lcnt_lo[idx] : lcnt_hi[idx];
      int v = (int)((word >> (8 * (e & 3))) & 255u);
      int s = v;
      #pragma unroll
      for (int d = 1; d < 64; d <<= 1) {
        int up = __shfl_up(s, d, 64);
        if (lane >= d) s += up;
      }
      pre[e * 256 + idx] = carry + s - v;
      carry += __shfl(s, 63, 64);
    }
    if (lane == 0) cnt8[e] = carry;
  }
  __syncthreads();

  if (t == 0) {
    int off = 0, tt2 = 0;
    for (int e = 0; e < NE; e++) {
      int cc = cnt8[e];
      meta[e] = cc;
      meta[8 + e] = off;
      offs8[e] = off;
      int ntl = (cc + BM3 - 1) / BM3;
      for (int i = 0; i < ntl; i++) meta[1024 + tt2++] = (e << 16) | i;
      off += cc;
    }
    meta[24] = tt2;
  }
  __syncthreads();

  unsigned int rlo = 0, rhi = 0;
  #pragma unroll
  for (int i = 0; i < 32; i++) {
    int g = (int)((gp[i >> 2] >> (8 * (i & 3))) & 255u);
    int r;
    if (g < 4) { r = (int)((rlo >> (8 * g)) & 255u);       rlo += 1u << (8 * g); }
    else       { r = (int)((rhi >> (8 * (g - 4))) & 255u); rhi += 1u << (8 * (g - 4)); }
    perm[offs8[g] + pre[g * 256 + t] + r] = t * 32 + i;
  }
}

// Fused 3-layer MLP per 32-row tile. 512 thr = 8 waves, ~1 block/CU (grid 263)
// so VGPR budget is 256/wave: W depth-3 (4-stage) + A depth-1 software
// pipeline, cross-layer W prologues issued before each barrier.
__global__ __launch_bounds__(512, 2)
void mlp_k(const float* __restrict__ h,
           const float* __restrict__ b1, const float* __restrict__ b2,
           const float* __restrict__ b3,
           float* __restrict__ out,
           const int* __restrict__ meta, const int* __restrict__ perm,
           const unsigned short* __restrict__ w1f,
           const unsigned short* __restrict__ w2f,
           const unsigned short* __restrict__ w3f)
{
  __shared__ unsigned short sA[BM3 * 520];   // h-tile (stride 520); a2 overlays (stride 264)
  __shared__ unsigned short sB[BM3 * 520];   // a1 (stride 520)
  __shared__ int permc[BM3];

  if ((int)blockIdx.x >= meta[24]) return;

  int tid  = threadIdx.x;
  int ent  = meta[1024 + blockIdx.x];
  int e    = ent >> 16;
  int trow = ent & 0xffff;
  int cnt  = meta[e];
  int off  = meta[8 + e];
  int row0 = trow * BM3;

  int wave = tid >> 6, lane = tid & 63;
  int lm = lane & 15, quad = lane >> 4;

  const unsigned short* W1b = w1f + (size_t)e * ND * NH1 + ((size_t)(wave * 4) * 64 + lane) * 8;
  const unsigned short* W2b = w2f + (size_t)e * NH1 * NH2 + ((size_t)(wave * 2) * 64 + lane) * 8;
  const unsigned short* W3b = w3f + (size_t)e * NH2 * NY + ((size_t)(wave * 2) * 64 + lane) * 8;

  bf16x8 w1s[4][4];
  bf16x8 w2s[4][2];
  bf16x8 w3s[4][2];

  // ---- W1 prologue (stages 0..2), no dependencies ----
  #pragma unroll
  for (int s = 0; s < 3; s++)
    #pragma unroll
    for (int ni = 0; ni < 4; ni++)
      w1s[s][ni] = *reinterpret_cast<const bf16x8*>(W1b + (size_t)s * 16384 + ni * 512);

  if (tid < BM3) {
    int grow = row0 + tid;
    permc[tid] = (grow < cnt) ? perm[off + grow] : 0;
  }
  __syncthreads();

  // ---- gather h-tile: 32 rows x 512 fp32 -> bf16 sA[32][520] ----
  {
    int r  = tid >> 4;
    int cb = (tid & 15) * 8;
    const float* hrow = h + (size_t)permc[r] * ND;
    #pragma unroll
    for (int jj = 0; jj < 4; jj++) {
      int col = cb + jj * 128;
      float4 f0 = *(const float4*)(hrow + col);
      float4 f1 = *(const float4*)(hrow + col + 4);
      union { u16x8 v; unsigned short u[8]; } pk;
      pk.u[0] = f2bf(f0.x); pk.u[1] = f2bf(f0.y); pk.u[2] = f2bf(f0.z); pk.u[3] = f2bf(f0.w);
      pk.u[4] = f2bf(f1.x); pk.u[5] = f2bf(f1.y); pk.u[6] = f2bf(f1.z); pk.u[7] = f2bf(f1.w);
      *(u16x8*)(sA + r * 520 + col) = pk.v;
    }
  }
  __syncthreads();

  f32x4 zero = {0.f, 0.f, 0.f, 0.f};

  // ---- Layer 1: sB = leaky(h x W1 + b1); n-slice 64; W depth-3 + A depth-1 ----
  {
    f32x4 acc[2][4];
    #pragma unroll
    for (int mi = 0; mi < 2; mi++)
      #pragma unroll
      for (int ni = 0; ni < 4; ni++)
        acc[mi][ni] = zero;
    bf16x8 ast[2][2];
    #pragma unroll
    for (int mi = 0; mi < 2; mi++)
      ast[0][mi] = *reinterpret_cast<const bf16x8*>(sA + (mi * 16 + lm) * 520 + quad * 8);
    #pragma unroll
    for (int t = 0; t < 16; t++) {
      int tw = (t + 3 < 16) ? t + 3 : 15;
      #pragma unroll
      for (int ni = 0; ni < 4; ni++)
        w1s[(t + 3) & 3][ni] = *reinterpret_cast<const bf16x8*>(W1b + (size_t)tw * 16384 + ni * 512);
      int ta = (t + 1 < 16) ? t + 1 : 15;
      #pragma unroll
      for (int mi = 0; mi < 2; mi++)
        ast[(t + 1) & 1][mi] = *reinterpret_cast<const bf16x8*>(sA + (mi * 16 + lm) * 520 + ta * 32 + quad * 8);
      #pragma unroll
      for (int mi = 0; mi < 2; mi++)
        #pragma unroll
        for (int ni = 0; ni < 4; ni++)
          acc[mi][ni] = __builtin_amdgcn_mfma_f32_16x16x32_bf16(ast[t & 1][mi], w1s[t & 3][ni], acc[mi][ni], 0, 0, 0);
    }
    // W2 prologue before the barrier
    #pragma unroll
    for (int s = 0; s < 3; s++)
      #pragma unroll
      for (int ni = 0; ni < 2; ni++)
        w2s[s][ni] = *reinterpret_cast<const bf16x8*>(W2b + (size_t)s * 8192 + ni * 512);
    #pragma unroll
    for (int mi = 0; mi < 2; mi++)
      #pragma unroll
      for (int ni = 0; ni < 4; ni++) {
        int col = (wave * 4 + ni) * 16 + lm;
        float bv = b1[e * NH1 + col];
        #pragma unroll
        for (int r = 0; r < 4; r++) {
          int row = mi * 16 + quad * 4 + r;
          float v = acc[mi][ni][r] + bv;
          v = (v > 0.f) ? v : 0.2f * v;
          sB[row * 520 + col] = f2bf(v);
        }
      }
  }
  __syncthreads();   // sB ready; all L1 reads of sA done

  // ---- Layer 2: a2 (overlay sA, stride 264); n-slice 32; W depth-3 + A depth-1 ----
  {
    f32x4 acc[2][2];
    #pragma unroll
    for (int mi = 0; mi < 2; mi++)
      #pragma unroll
      for (int ni = 0; ni < 2; ni++)
        acc[mi][ni] = zero;
    bf16x8 ast[2][2];
    #pragma unroll
    for (int mi = 0; mi < 2; mi++)
      ast[0][mi] = *reinterpret_cast<const bf16x8*>(sB + (mi * 16 + lm) * 520 + quad * 8);
    #pragma unroll
    for (int t = 0; t < 16; t++) {
      int tw = (t + 3 < 16) ? t + 3 : 15;
      #pragma unroll
      for (int ni = 0; ni < 2; ni++)
        w2s[(t + 3) & 3][ni] = *reinterpret_cast<const bf16x8*>(W2b + (size_t)tw * 8192 + ni * 512);
      int ta = (t + 1 < 16) ? t + 1 : 15;
      #pragma unroll
      for (int mi = 0; mi < 2; mi++)
        ast[(t + 1) & 1][mi] = *reinterpret_cast<const bf16x8*>(sB + (mi * 16 + lm) * 520 + ta * 32 + quad * 8);
      #pragma unroll
      for (int mi = 0; mi < 2; mi++)
        #pragma unroll
        for (int ni = 0; ni < 2; ni++)
          acc[mi][ni] = __builtin_amdgcn_mfma_f32_16x16x32_bf16(ast[t & 1][mi], w2s[t & 3][ni], acc[mi][ni], 0, 0, 0);
    }
    // W3 prologue before the barrier
    #pragma unroll
    for (int s = 0; s < 3; s++)
      #pragma unroll
      for (int ni = 0; ni < 2; ni++)
        w3s[s][ni] = *reinterpret_cast<const bf16x8*>(W3b + (size_t)s * 8192 + ni * 512);
    #pragma unroll
    for (int mi = 0; mi < 2; mi++)
      #pragma unroll
      for (int ni = 0; ni < 2; ni++) {
        int col = (wave * 2 + ni) * 16 + lm;
        float bv = b2[e * NH2 + col];
        #pragma unroll
        for (int r = 0; r < 4; r++) {
          int row = mi * 16 + quad * 4 + r;
          float v = acc[mi][ni][r] + bv;
          v = (v > 0.f) ? v : 0.2f * v;
          sA[row * 264 + col] = f2bf(v);
        }
      }
  }
  __syncthreads();   // a2 ready

  // ---- Layer 3: out = a2 x W3 + b3 (scatter); n-slice 32; W depth-3 + A depth-1 ----
  {
    f32x4 acc[2][2];
    #pragma unroll
    for (int mi = 0; mi < 2; mi++)
      #pragma unroll
      for (int ni = 0; ni < 2; ni++)
        acc[mi][ni] = zero;
    bf16x8 ast[2][2];
    #pragma unroll
    for (int mi = 0; mi < 2; mi++)
      ast[0][mi] = *reinterpret_cast<const bf16x8*>(sA + (mi * 16 + lm) * 264 + quad * 8);
    #pragma unroll
    for (int t = 0; t < 8; t++) {
      int tw = (t + 3 < 8) ? t + 3 : 7;
      #pragma unroll
      for (int ni = 0; ni < 2; ni++)
        w3s[(t + 3) & 3][ni] = *reinterpret_cast<const bf16x8*>(W3b + (size_t)tw * 8192 + ni * 512);
      int ta = (t + 1 < 8) ? t + 1 : 7;
      #pragma unroll
      for (int mi = 0; mi < 2; mi++)
        ast[(t + 1) & 1][mi] = *reinterpret_cast<const bf16x8*>(sA + (mi * 16 + lm) * 264 + ta * 32 + quad * 8);
      #pragma unroll
      for (int mi = 0; mi < 2; mi++)
        #pragma unroll
        for (int ni = 0; ni < 2; ni++)
          acc[mi][ni] = __builtin_amdgcn_mfma_f32_16x16x32_bf16(ast[t & 1][mi], w3s[t & 3][ni], acc[mi][ni], 0, 0, 0);
    }
    #pragma unroll
    for (int mi = 0; mi < 2; mi++)
      #pragma unroll
      for (int ni = 0; ni < 2; ni++) {
        int col = (wave * 2 + ni) * 16 + lm;
        float bv = b3[e * NY + col];
        #pragma unroll
        for (int r = 0; r < 4; r++) {
          int row = mi * 16 + quad * 4 + r;
          int grow = row0 + row;
          if (grow < cnt) {
            float v = acc[mi][ni][r] + bv;
            out[(size_t)permc[row] * NY + col] = v;
          }
        }
      }
  }
}

extern "C" void kernel_launch(void* const* d_in, const int* in_sizes, int n_in,
                              void* d_out, int out_size, void* d_ws, size_t ws_size,
                              hipStream_t stream) {
  (void)in_sizes; (void)n_in; (void)out_size; (void)ws_size;
  const float* h  = (const float*)d_in[0];
  const int* gate = (const int*)d_in[1];
  const float* W1 = (const float*)d_in[2];
  const float* b1 = (const float*)d_in[3];
  const float* W2 = (const float*)d_in[4];
  const float* b2 = (const float*)d_in[5];
  const float* W3 = (const float*)d_in[6];
  const float* b3 = (const float*)d_in[7];
  float* out = (float*)d_out;

  char* ws = (char*)d_ws;
  int* meta = (int*)ws;                               // 8 KB
  int* perm = (int*)(ws + 8192);                      // 32 KB
  unsigned short* w1f = (unsigned short*)(ws + 8192 + 32768);
  unsigned short* w2f = w1f + (size_t)NE * ND * NH1;
  unsigned short* w3f = w2f + (size_t)NE * NH1 * NH2;
  // ws total ~7.2 MB

  prep_k<<<WTT64 + 1, 256, 0, stream>>>(gate, W1, W2, W3, w1f, w2f, w3f, meta, perm);
  mlp_k<<<MAXT3, 512, 0, stream>>>(h, b1, b2, b3, out, meta, perm, w1f, w2f, w3f);
}

// Round 14
// 119.473 us; speedup vs baseline: 1.0962x; 1.0962x over previous
//
#include <hip/hip_runtime.h>
#include <stdint.h>

#define NE 8
#define ND 512
#define NH1 512
#define NH2 256
#define NY 256
#define NB 8192
#define BM3 32                   /* fused-tile rows */
#define MAXT3 (NB/BM3 + NE - 1)  /* 263 */
/* 64x64 transpose tiles */
#define W1T64 (NE * (ND/64) * (NH1/64))   /* 512 */
#define W2T64 (NE * (NH1/64) * (NH2/64))  /* 256 */
#define W3T64 (NE * (NH2/64) * (NY/64))   /* 128 */
#define WTT64 (W1T64 + W2T64 + W3T64)     /* 896 */

typedef float f32x4 __attribute__((ext_vector_type(4)));
typedef __bf16 bf16x8 __attribute__((ext_vector_type(8)));
typedef unsigned short u16x8 __attribute__((ext_vector_type(8)));

__device__ __forceinline__ unsigned short f2bf(float f) {
  unsigned int u = __float_as_uint(f);
  u += 0x7fffu + ((u >> 16) & 1u);   // round-to-nearest-even
  return (unsigned short)(u >> 16);
}

__device__ __forceinline__ int clampe(int g) {
  return g < 0 ? 0 : (g > NE - 1 ? NE - 1 : g);
}

// Fragment-order W layout: element (k = kt*32 + (lane>>4)*8 + j, n = f*16 + (lane&15))
// lives at Wf[(((kt * (N/16)) + f) * 64 + lane) * 8 + j]. One wave-load of frag
// (kt,f) = 64 lanes x 16B = 1KB fully contiguous.

// meta ints: [0..7] counts, [8..15] offs, [24] ntiles, [1024..1310] tile table

// prep_k: 256 thr/block. Blocks 0..895: 64x64 W transpose tiles (float4 in,
// 16B frag-order out). Block 896: deterministic counting sort, 32 rows/thread.
__global__ __launch_bounds__(256)
void prep_k(const int* __restrict__ gate,
            const float* __restrict__ W1, const float* __restrict__ W2,
            const float* __restrict__ W3,
            unsigned short* __restrict__ w1f, unsigned short* __restrict__ w2f,
            unsigned short* __restrict__ w3f,
            int* __restrict__ meta, int* __restrict__ perm)
{
  __shared__ char sm[17024] __attribute__((aligned(16)));
  int b = blockIdx.x, t = threadIdx.x;

  if (b < WTT64) {
    float* ldsf = (float*)sm;   // [64][65]
    const float* src; unsigned short* dst; int K, N, idx;
    if (b < W1T64)          { src = W1; dst = w1f; K = ND;  N = NH1; idx = b; }
    else if (b < W1T64 + W2T64) { src = W2; dst = w2f; K = NH1; N = NH2; idx = b - W1T64; }
    else                    { src = W3; dst = w3f; K = NH2; N = NY;  idx = b - W1T64 - W2T64; }
    int ntn = N >> 6, ntk = K >> 6;
    int n0 = (idx % ntn) * 64;
    int k0 = ((idx / ntn) % ntk) * 64;
    int g  = idx / (ntn * ntk);

    // read: 64 rows x 16 float4; r = t>>2, 4 lanes x 4 iters per row
    {
      int r  = t >> 2;
      int c4 = t & 3;
      const float* s = src + (size_t)g * K * N + (size_t)(k0 + r) * N + n0;
      #pragma unroll
      for (int i = 0; i < 4; i++) {
        float4 v = *(const float4*)(s + (i * 4 + c4) * 4);
        *(float4*)(ldsf + r * 65 + (i * 4 + c4) * 4) = v;
      }
    }
    __syncthreads();

    // write: 512 frag-rows of 8 bf16; idx -> (kt 0..1, f 0..3, lane)
    unsigned short* d = dst + (size_t)g * K * N;
    #pragma unroll
    for (int ii = 0; ii < 2; ii++) {
      int idx2 = ii * 256 + t;
      int lane = idx2 & 63;
      int f    = (idx2 >> 6) & 3;
      int kt   = idx2 >> 8;
      int kl   = kt * 32 + (lane >> 4) * 8;   // k_local base
      int nl   = f * 16 + (lane & 15);        // n_local
      union { u16x8 v; unsigned short u[8]; } pk;
      #pragma unroll
      for (int j = 0; j < 8; j++)
        pk.u[j] = f2bf(ldsf[(kl + j) * 65 + nl]);
      int ktg = (k0 >> 5) + kt;
      int fg  = (n0 >> 4) + f;
      *(u16x8*)(d + (((size_t)ktg * (N >> 4) + fg) * 64 + lane) * 8) = pk.v;
    }
    return;
  }

  // ---- sort block: 256 threads x 32 rows each (deterministic, no global atomics) ----
  unsigned int* lcnt_lo = (unsigned int*)sm;           // [256]
  unsigned int* lcnt_hi = lcnt_lo + 256;               // [256]
  int* pre   = (int*)(sm + 2048);                      // [NE][256] = 8KB
  int* cnt8  = (int*)(sm + 2048 + 8192);               // [8]
  int* offs8 = cnt8 + 8;                               // [8]

  unsigned int gp[8];   // 32 gates, byte-packed
  unsigned int clo = 0, chi = 0;
  #pragma unroll
  for (int i = 0; i < 32; i++) {
    int g = clampe(gate[t * 32 + i]);
    if ((i & 3) == 0) gp[i >> 2] = 0;
    gp[i >> 2] |= (unsigned int)g << (8 * (i & 3));
    if (g < 4) clo += 1u << (8 * g);
    else       chi += 1u << (8 * (g - 4));
  }
  lcnt_lo[t] = clo;
  lcnt_hi[t] = chi;
  __syncthreads();

  int wave = t >> 6, lane = t & 63;
  #pragma unroll
  for (int pass = 0; pass < 2; pass++) {
    int e = wave + pass * 4;
    int carry = 0;
    #pragma unroll
    for (int ch = 0; ch < 4; ch++) {
      int idx = ch * 64 + lane;
      unsigned int word = (e < 4) ? lcnt_lo[idx] : lcnt_hi[idx];
      int v = (int)((word >> (8 * (e & 3))) & 255u);
      int s = v;
      #pragma unroll
      for (int d = 1; d < 64; d <<= 1) {
        int up = __shfl_up(s, d, 64);
        if (lane >= d) s += up;
      }
      pre[e * 256 + idx] = carry + s - v;   // exclusive prefix
      carry += __shfl(s, 63, 64);
    }
    if (lane == 0) cnt8[e] = carry;
  }
  __syncthreads();

  if (t == 0) {
    int off = 0, tt2 = 0;
    for (int e = 0; e < NE; e++) {
      int cc = cnt8[e];
      meta[e] = cc;
      meta[8 + e] = off;
      offs8[e] = off;
      int ntl = (cc + BM3 - 1) / BM3;
      for (int i = 0; i < ntl; i++) meta[1024 + tt2++] = (e << 16) | i;
      off += cc;
    }
    meta[24] = tt2;
  }
  __syncthreads();

  unsigned int rlo = 0, rhi = 0;
  #pragma unroll
  for (int i = 0; i < 32; i++) {
    int g = (int)((gp[i >> 2] >> (8 * (i & 3))) & 255u);
    int r;
    if (g < 4) { r = (int)((rlo >> (8 * g)) & 255u);       rlo += 1u << (8 * g); }
    else       { r = (int)((rhi >> (8 * (g - 4))) & 255u); rhi += 1u << (8 * (g - 4)); }
    perm[offs8[g] + pre[g * 256 + t] + r] = t * 32 + i;
  }
}

// Fused 3-layer MLP per 32-row tile (R12 champion structure, verbatim).
// 512 thr = 8 waves; W via frag-order coalesced 1KB wave-loads, depth-1
// pipeline (depth>=2 measured regression: R9 -7us, R13 -11us — compiler
// drains vmcnt(0) at barriers, deeper manual pipelines only add VGPRs).
// out scatter uses non-temporal stores to keep expert W resident in L2.
__global__ __launch_bounds__(512, 6)
void mlp_k(const float* __restrict__ h,
           const float* __restrict__ b1, const float* __restrict__ b2,
           const float* __restrict__ b3,
           float* __restrict__ out,
           const int* __restrict__ meta, const int* __restrict__ perm,
           const unsigned short* __restrict__ w1f,
           const unsigned short* __restrict__ w2f,
           const unsigned short* __restrict__ w3f)
{
  __shared__ unsigned short sA[BM3 * 520];   // h-tile (stride 520); a2 overlays (stride 264)
  __shared__ unsigned short sB[BM3 * 520];   // a1 (stride 520)
  __shared__ int permc[BM3];

  if ((int)blockIdx.x >= meta[24]) return;

  int tid  = threadIdx.x;
  int ent  = meta[1024 + blockIdx.x];
  int e    = ent >> 16;
  int trow = ent & 0xffff;
  int cnt  = meta[e];
  int off  = meta[8 + e];
  int row0 = trow * BM3;

  if (tid < BM3) {
    int grow = row0 + tid;
    permc[tid] = (grow < cnt) ? perm[off + grow] : 0;
  }
  __syncthreads();

  int wave = tid >> 6, lane = tid & 63;
  int lm = lane & 15, quad = lane >> 4;

  // ---- gather h-tile: 32 rows x 512 fp32 -> bf16 sA[32][520] ----
  {
    int r  = tid >> 4;             // 0..31
    int cb = (tid & 15) * 8;       // 0..120
    const float* hrow = h + (size_t)permc[r] * ND;
    #pragma unroll
    for (int jj = 0; jj < 4; jj++) {
      int col = cb + jj * 128;
      float4 f0 = *(const float4*)(hrow + col);
      float4 f1 = *(const float4*)(hrow + col + 4);
      union { u16x8 v; unsigned short u[8]; } pk;
      pk.u[0] = f2bf(f0.x); pk.u[1] = f2bf(f0.y); pk.u[2] = f2bf(f0.z); pk.u[3] = f2bf(f0.w);
      pk.u[4] = f2bf(f1.x); pk.u[5] = f2bf(f1.y); pk.u[6] = f2bf(f1.z); pk.u[7] = f2bf(f1.w);
      *(u16x8*)(sA + r * 520 + col) = pk.v;
    }
  }
  __syncthreads();

  f32x4 zero = {0.f, 0.f, 0.f, 0.f};

  // ---- Layer 1: sB = leaky(h x W1 + b1); wave n-slice 64; depth-1 pipeline ----
  {
    f32x4 acc[2][4];
    #pragma unroll
    for (int mi = 0; mi < 2; mi++)
      #pragma unroll
      for (int ni = 0; ni < 4; ni++)
        acc[mi][ni] = zero;
    const unsigned short* Wb = w1f + (size_t)e * ND * NH1 + ((size_t)(wave * 4) * 64 + lane) * 8;
    bf16x8 cur[4], nxt[4];
    #pragma unroll
    for (int ni = 0; ni < 4; ni++)
      cur[ni] = *reinterpret_cast<const bf16x8*>(Wb + ni * 512);
    for (int t = 0; t < 16; t++) {
      int tn = (t + 1 < 16) ? t + 1 : t;
      #pragma unroll
      for (int ni = 0; ni < 4; ni++)
        nxt[ni] = *reinterpret_cast<const bf16x8*>(Wb + (size_t)tn * 16384 + ni * 512);
      bf16x8 af[2];
      #pragma unroll
      for (int mi = 0; mi < 2; mi++)
        af[mi] = *reinterpret_cast<const bf16x8*>(sA + (mi * 16 + lm) * 520 + t * 32 + quad * 8);
      #pragma unroll
      for (int mi = 0; mi < 2; mi++)
        #pragma unroll
        for (int ni = 0; ni < 4; ni++)
          acc[mi][ni] = __builtin_amdgcn_mfma_f32_16x16x32_bf16(af[mi], cur[ni], acc[mi][ni], 0, 0, 0);
      #pragma unroll
      for (int ni = 0; ni < 4; ni++)
        cur[ni] = nxt[ni];
    }
    #pragma unroll
    for (int mi = 0; mi < 2; mi++)
      #pragma unroll
      for (int ni = 0; ni < 4; ni++) {
        int col = (wave * 4 + ni) * 16 + lm;
        float bv = b1[e * NH1 + col];
        #pragma unroll
        for (int r = 0; r < 4; r++) {
          int row = mi * 16 + quad * 4 + r;
          float v = acc[mi][ni][r] + bv;
          v = (v > 0.f) ? v : 0.2f * v;
          sB[row * 520 + col] = f2bf(v);
        }
      }
  }
  __syncthreads();   // sB ready; all L1 reads of sA done

  // ---- Layer 2: a2 (overlay sA, stride 264) = leaky(a1 x W2 + b2); n-slice 32 ----
  {
    f32x4 acc[2][2];
    #pragma unroll
    for (int mi = 0; mi < 2; mi++)
      #pragma unroll
      for (int ni = 0; ni < 2; ni++)
        acc[mi][ni] = zero;
    const unsigned short* Wb = w2f + (size_t)e * NH1 * NH2 + ((size_t)(wave * 2) * 64 + lane) * 8;
    bf16x8 cur[2], nxt[2];
    #pragma unroll
    for (int ni = 0; ni < 2; ni++)
      cur[ni] = *reinterpret_cast<const bf16x8*>(Wb + ni * 512);
    for (int t = 0; t < 16; t++) {
      int tn = (t + 1 < 16) ? t + 1 : t;
      #pragma unroll
      for (int ni = 0; ni < 2; ni++)
        nxt[ni] = *reinterpret_cast<const bf16x8*>(Wb + (size_t)tn * 8192 + ni * 512);
      bf16x8 af[2];
      #pragma unroll
      for (int mi = 0; mi < 2; mi++)
        af[mi] = *reinterpret_cast<const bf16x8*>(sB + (mi * 16 + lm) * 520 + t * 32 + quad * 8);
      #pragma unroll
      for (int mi = 0; mi < 2; mi++)
        #pragma unroll
        for (int ni = 0; ni < 2; ni++)
          acc[mi][ni] = __builtin_amdgcn_mfma_f32_16x16x32_bf16(af[mi], cur[ni], acc[mi][ni], 0, 0, 0);
      #pragma unroll
      for (int ni = 0; ni < 2; ni++)
        cur[ni] = nxt[ni];
    }
    #pragma unroll
    for (int mi = 0; mi < 2; mi++)
      #pragma unroll
      for (int ni = 0; ni < 2; ni++) {
        int col = (wave * 2 + ni) * 16 + lm;
        float bv = b2[e * NH2 + col];
        #pragma unroll
        for (int r = 0; r < 4; r++) {
          int row = mi * 16 + quad * 4 + r;
          float v = acc[mi][ni][r] + bv;
          v = (v > 0.f) ? v : 0.2f * v;
          sA[row * 264 + col] = f2bf(v);   // safe: L1 reads of sA complete
        }
      }
  }
  __syncthreads();   // a2 ready

  // ---- Layer 3: out = a2 x W3 + b3 (nt scatter); n-slice 32 ----
  {
    f32x4 acc[2][2];
    #pragma unroll
    for (int mi = 0; mi < 2; mi++)
      #pragma unroll
      for (int ni = 0; ni < 2; ni++)
        acc[mi][ni] = zero;
    const unsigned short* Wb = w3f + (size_t)e * NH2 * NY + ((size_t)(wave * 2) * 64 + lane) * 8;
    bf16x8 cur[2], nxt[2];
    #pragma unroll
    for (int ni = 0; ni < 2; ni++)
      cur[ni] = *reinterpret_cast<const bf16x8*>(Wb + ni * 512);
    for (int t = 0; t < 8; t++) {
      int tn = (t + 1 < 8) ? t + 1 : t;
      #pragma unroll
      for (int ni = 0; ni < 2; ni++)
        nxt[ni] = *reinterpret_cast<const bf16x8*>(Wb + (size_t)tn * 8192 + ni * 512);
      bf16x8 af[2];
      #pragma unroll
      for (int mi = 0; mi < 2; mi++)
        af[mi] = *reinterpret_cast<const bf16x8*>(sA + (mi * 16 + lm) * 264 + t * 32 + quad * 8);
      #pragma unroll
      for (int mi = 0; mi < 2; mi++)
        #pragma unroll
        for (int ni = 0; ni < 2; ni++)
          acc[mi][ni] = __builtin_amdgcn_mfma_f32_16x16x32_bf16(af[mi], cur[ni], acc[mi][ni], 0, 0, 0);
      #pragma unroll
      for (int ni = 0; ni < 2; ni++)
        cur[ni] = nxt[ni];
    }
    #pragma unroll
    for (int mi = 0; mi < 2; mi++)
      #pragma unroll
      for (int ni = 0; ni < 2; ni++) {
        int col = (wave * 2 + ni) * 16 + lm;
        float bv = b3[e * NY + col];
        #pragma unroll
        for (int r = 0; r < 4; r++) {
          int row = mi * 16 + quad * 4 + r;
          int grow = row0 + row;
          if (grow < cnt) {
            float v = acc[mi][ni][r] + bv;
            __builtin_nontemporal_store(v, &out[(size_t)permc[row] * NY + col]);
          }
        }
      }
  }
}

extern "C" void kernel_launch(void* const* d_in, const int* in_sizes, int n_in,
                              void* d_out, int out_size, void* d_ws, size_t ws_size,
                              hipStream_t stream) {
  (void)in_sizes; (void)n_in; (void)out_size; (void)ws_size;
  const float* h  = (const float*)d_in[0];
  const int* gate = (const int*)d_in[1];
  const float* W1 = (const float*)d_in[2];
  const float* b1 = (const float*)d_in[3];
  const float* W2 = (const float*)d_in[4];
  const float* b2 = (const float*)d_in[5];
  const float* W3 = (const float*)d_in[6];
  const float* b3 = (const float*)d_in[7];
  float* out = (float*)d_out;

  char* ws = (char*)d_ws;
  int* meta = (int*)ws;                               // 8 KB
  int* perm = (int*)(ws + 8192);                      // 32 KB
  unsigned short* w1f = (unsigned short*)(ws + 8192 + 32768);
  unsigned short* w2f = w1f + (size_t)NE * ND * NH1;
  unsigned short* w3f = w2f + (size_t)NE * NH1 * NH2;
  // ws total ~7.2 MB

  prep_k<<<WTT64 + 1, 256, 0, stream>>>(gate, W1, W2, W3, w1f, w2f, w3f, meta, perm);
  mlp_k<<<MAXT3, 512, 0, stream>>>(h, b1, b2, b3, out, meta, perm, w1f, w2f, w3f);
}